// Round 1
// baseline (521.428 us; speedup 1.0000x reference)
//
#include <hip/hip_runtime.h>

#define HID 512
#define BM 128
#define BN 128
#define BK 32
#define LPAD 40   // LDS row stride in bf16 elems (80B = 20 banks -> conflict-spread)

typedef unsigned int uint32;
typedef unsigned short ushort16;
using bf16x8 = __attribute__((ext_vector_type(8))) short;
using f32x4  = __attribute__((ext_vector_type(4))) float;
typedef __attribute__((ext_vector_type(8))) unsigned short ushort8v;

__device__ __forceinline__ unsigned short f2bf(float f) {
    uint32 u = __float_as_uint(f);
    uint32 r = (u + 0x7FFFu + ((u >> 16) & 1u)) >> 16;   // RNE
    return (unsigned short)r;
}
__device__ __forceinline__ float bf2f(unsigned short u) {
    return __uint_as_float(((uint32)u) << 16);
}

// ---------------- counters init ----------------
__global__ void init_counts(int* cnt, int* fill, int n) {
    int i = blockIdx.x * 256 + threadIdx.x;
    if (i < n) { cnt[i] = 0; fill[i] = 0; }
}

// ---------------- in-degree count (dst only, matches reference) ----------------
__global__ void count_deg(const int* __restrict__ dst, int* __restrict__ cnt, int e) {
    int i = blockIdx.x * 256 + threadIdx.x;
    if (i < e) atomicAdd(&cnt[dst[i]], 1);
}

// ---------------- 3-phase exclusive scan of cnt -> rowstart ----------------
__global__ __launch_bounds__(1024) void scan1(const int* __restrict__ cnt,
                                              int* __restrict__ rowstart,
                                              int* __restrict__ bsum, int n) {
    __shared__ int sh[1024];
    int i = blockIdx.x * 1024 + threadIdx.x;
    int x = (i < n) ? cnt[i] : 0;
    sh[threadIdx.x] = x;
    __syncthreads();
    for (int off = 1; off < 1024; off <<= 1) {
        int y = 0;
        if ((int)threadIdx.x >= off) y = sh[threadIdx.x - off];
        __syncthreads();
        sh[threadIdx.x] += y;
        __syncthreads();
    }
    if (i < n) rowstart[i] = sh[threadIdx.x] - x;   // exclusive
    if (threadIdx.x == 1023) bsum[blockIdx.x] = sh[1023];
}

__global__ void scan2(int* bsum, int nb) {
    if (threadIdx.x == 0 && blockIdx.x == 0) {
        int run = 0;
        for (int i = 0; i < nb; ++i) { int v = bsum[i]; bsum[i] = run; run += v; }
    }
}

__global__ void scan3(int* __restrict__ rowstart, const int* __restrict__ bsum,
                      const int* __restrict__ cnt, float* __restrict__ dinv, int n) {
    int i = blockIdx.x * 256 + threadIdx.x;
    if (i < n) {
        rowstart[i] += bsum[i >> 10];
        dinv[i] = rsqrtf((float)(cnt[i] + 1));   // +1 self loop; always > 0
    }
}

// ---------------- CSR fill (bucket order nondeterministic; f32 sum within threshold) ----
__global__ void csr_fill(const int* __restrict__ src, const int* __restrict__ dst,
                         const int* __restrict__ rowstart, int* __restrict__ fill,
                         int* __restrict__ csr, int e) {
    int i = blockIdx.x * 256 + threadIdx.x;
    if (i < e) {
        int d = dst[i];
        int p = atomicAdd(&fill[d], 1);
        csr[rowstart[d] + p] = src[i];
    }
}

// ---------------- W transpose + bf16 convert: Wt[n][k] = bf16(W[k][n]) ----------------
__global__ void w_transpose(const float* __restrict__ W, unsigned short* __restrict__ Wt) {
    int idx = blockIdx.x * 256 + threadIdx.x;
    if (idx < HID * HID) {
        int k = idx >> 9, n = idx & (HID - 1);
        Wt[n * HID + k] = f2bf(W[k * HID + n]);
    }
}

// ---------------- GEMM: hs[n][c] = bf16( (X@W)[n][c] * dinv[n] ) ----------------
__global__ __launch_bounds__(256) void gemm_xw(const float* __restrict__ X,
                                               const unsigned short* __restrict__ Wt,
                                               const float* __restrict__ dinv,
                                               unsigned short* __restrict__ hs, int M) {
    __shared__ unsigned short Alds[BM * LPAD];
    __shared__ unsigned short Blds[BN * LPAD];
    const int t = threadIdx.x;
    const int lane = t & 63, wid = t >> 6;
    const int wm = wid >> 1, wn = wid & 1;          // 2x2 waves -> 64x64 each
    const int row_base = blockIdx.x * BM;
    const int col_base = blockIdx.y * BN;

    f32x4 acc[4][4];
    #pragma unroll
    for (int m = 0; m < 4; ++m)
        #pragma unroll
        for (int n = 0; n < 4; ++n)
            acc[m][n] = (f32x4){0.f, 0.f, 0.f, 0.f};

    const int kgr = (lane >> 4) * 8;
    const int rr = lane & 15;

    for (int k0 = 0; k0 < HID; k0 += BK) {
        // stage A: 128 rows x 32 k (f32 -> bf16)
        #pragma unroll
        for (int i = 0; i < 4; ++i) {
            int f = t + 256 * i;            // 0..1023
            int r = f >> 3;                 // 0..127
            int kq = (f & 7) * 4;           // 0..28
            int grow = row_base + r;
            float4 v = make_float4(0.f, 0.f, 0.f, 0.f);
            if (grow < M) v = *(const float4*)(X + (size_t)grow * HID + k0 + kq);
            ushort4 w;
            w.x = f2bf(v.x); w.y = f2bf(v.y); w.z = f2bf(v.z); w.w = f2bf(v.w);
            *(ushort4*)&Alds[r * LPAD + kq] = w;
        }
        // stage B: 128 cols x 32 k from pre-transposed bf16 Wt
        #pragma unroll
        for (int i = 0; i < 4; ++i) {
            int f = t + 256 * i;
            int c = f >> 3;
            int kq = (f & 7) * 4;
            ushort4 w = *(const ushort4*)(Wt + (size_t)(col_base + c) * HID + k0 + kq);
            *(ushort4*)&Blds[c * LPAD + kq] = w;
        }
        __syncthreads();

        bf16x8 afr[4], bfr[4];
        #pragma unroll
        for (int m = 0; m < 4; ++m)
            afr[m] = *(const bf16x8*)&Alds[(wm * 64 + m * 16 + rr) * LPAD + kgr];
        #pragma unroll
        for (int n = 0; n < 4; ++n)
            bfr[n] = *(const bf16x8*)&Blds[(wn * 64 + n * 16 + rr) * LPAD + kgr];
        #pragma unroll
        for (int m = 0; m < 4; ++m)
            #pragma unroll
            for (int n = 0; n < 4; ++n)
                acc[m][n] = __builtin_amdgcn_mfma_f32_16x16x32_bf16(afr[m], bfr[n], acc[m][n], 0, 0, 0);
        __syncthreads();
    }

    // epilogue: D mapping col = lane&15, row = (lane>>4)*4 + reg
    const int rgrp = (lane >> 4) * 4;
    const int cc = lane & 15;
    #pragma unroll
    for (int m = 0; m < 4; ++m) {
        #pragma unroll
        for (int r = 0; r < 4; ++r) {
            int grow = row_base + wm * 64 + m * 16 + rgrp + r;
            if (grow >= M) continue;
            float g = dinv[grow];
            #pragma unroll
            for (int n = 0; n < 4; ++n) {
                int gcol = col_base + wn * 64 + n * 16 + cc;
                hs[(size_t)grow * HID + gcol] = f2bf(acc[m][n][r] * g);
            }
        }
    }
}

// ---------------- fused: gather-aggregate + dinv scale + b + residual + LayerNorm ----
__global__ __launch_bounds__(256) void agg_ln(const unsigned short* __restrict__ hs,
                                              const float* __restrict__ resid,
                                              const float* __restrict__ bvec,
                                              const float* __restrict__ gamma,
                                              const float* __restrict__ beta,
                                              const int* __restrict__ rowstart,
                                              const int* __restrict__ cnt,
                                              const float* __restrict__ dinv,
                                              const int* __restrict__ csr,
                                              float* __restrict__ out, int nn) {
    const int wave = threadIdx.x >> 6;
    const int lane = threadIdx.x & 63;
    const int n = blockIdx.x * 4 + wave;
    if (n >= nn) return;
    const int c0 = lane * 8;

    float acc[8];
    {   // self-loop message: hs already includes dinv[src]
        ushort8v v = *(const ushort8v*)(hs + (size_t)n * HID + c0);
        #pragma unroll
        for (int j = 0; j < 8; ++j) acc[j] = bf2f(v[j]);
    }
    const int s0 = rowstart[n];
    const int m = cnt[n];
    const int* idx = csr + s0;
    int i = 0;
    for (; i + 4 <= m; i += 4) {
        int sa = idx[i], sb = idx[i + 1], sc = idx[i + 2], sd = idx[i + 3];
        ushort8v va = *(const ushort8v*)(hs + (size_t)sa * HID + c0);
        ushort8v vb = *(const ushort8v*)(hs + (size_t)sb * HID + c0);
        ushort8v vc = *(const ushort8v*)(hs + (size_t)sc * HID + c0);
        ushort8v vd = *(const ushort8v*)(hs + (size_t)sd * HID + c0);
        #pragma unroll
        for (int j = 0; j < 8; ++j)
            acc[j] += (bf2f(va[j]) + bf2f(vb[j])) + (bf2f(vc[j]) + bf2f(vd[j]));
    }
    for (; i < m; ++i) {
        int s = idx[i];
        ushort8v v = *(const ushort8v*)(hs + (size_t)s * HID + c0);
        #pragma unroll
        for (int j = 0; j < 8; ++j) acc[j] += bf2f(v[j]);
    }

    const float g = dinv[n];
    float4 r0 = *(const float4*)(resid + (size_t)n * HID + c0);
    float4 r1 = *(const float4*)(resid + (size_t)n * HID + c0 + 4);
    float val[8];
    val[0] = r0.x + g * acc[0] + bvec[c0 + 0];
    val[1] = r0.y + g * acc[1] + bvec[c0 + 1];
    val[2] = r0.z + g * acc[2] + bvec[c0 + 2];
    val[3] = r0.w + g * acc[3] + bvec[c0 + 3];
    val[4] = r1.x + g * acc[4] + bvec[c0 + 4];
    val[5] = r1.y + g * acc[5] + bvec[c0 + 5];
    val[6] = r1.z + g * acc[6] + bvec[c0 + 6];
    val[7] = r1.w + g * acc[7] + bvec[c0 + 7];

    float s = 0.f, q = 0.f;
    #pragma unroll
    for (int j = 0; j < 8; ++j) { s += val[j]; q += val[j] * val[j]; }
    #pragma unroll
    for (int off = 32; off > 0; off >>= 1) {
        s += __shfl_xor(s, off, 64);
        q += __shfl_xor(q, off, 64);
    }
    const float mean = s * (1.f / 512.f);
    const float var = q * (1.f / 512.f) - mean * mean;
    const float rstd = rsqrtf(var + 1e-5f);

    float4 o0, o1;
    o0.x = (val[0] - mean) * rstd * gamma[c0 + 0] + beta[c0 + 0];
    o0.y = (val[1] - mean) * rstd * gamma[c0 + 1] + beta[c0 + 1];
    o0.z = (val[2] - mean) * rstd * gamma[c0 + 2] + beta[c0 + 2];
    o0.w = (val[3] - mean) * rstd * gamma[c0 + 3] + beta[c0 + 3];
    o1.x = (val[4] - mean) * rstd * gamma[c0 + 4] + beta[c0 + 4];
    o1.y = (val[5] - mean) * rstd * gamma[c0 + 5] + beta[c0 + 5];
    o1.z = (val[6] - mean) * rstd * gamma[c0 + 6] + beta[c0 + 6];
    o1.w = (val[7] - mean) * rstd * gamma[c0 + 7] + beta[c0 + 7];
    *(float4*)(out + (size_t)n * HID + c0) = o0;
    *(float4*)(out + (size_t)n * HID + c0 + 4) = o1;
}

extern "C" void kernel_launch(void* const* d_in, const int* in_sizes, int n_in,
                              void* d_out, int out_size, void* d_ws, size_t ws_size,
                              hipStream_t stream) {
    const float* X     = (const float*)d_in[0];   // label_emb [N][512], also residual
    const int*   edges = (const int*)d_in[1];     // [2][E]
    const float* W     = (const float*)d_in[2];   // [512][512]
    const float* b     = (const float*)d_in[3];
    const float* gamma = (const float*)d_in[4];
    const float* beta  = (const float*)d_in[5];
    float* out = (float*)d_out;

    const int E = in_sizes[1] / 2;
    const int N = in_sizes[0] / HID;
    const int* src = edges;
    const int* dst = edges + E;

    // workspace layout
    char* w = (char*)d_ws;
    auto alloc = [&](size_t bytes) { char* p = w; w += (bytes + 255) & ~(size_t)255; return p; };
    int*   cnt      = (int*)alloc((size_t)N * 4);
    int*   fill     = (int*)alloc((size_t)N * 4);
    int*   rowstart = (int*)alloc((size_t)N * 4);
    int*   bsum     = (int*)alloc(256 * 4);
    float* dinv     = (float*)alloc((size_t)N * 4);
    int*   csr      = (int*)alloc((size_t)E * 4);
    unsigned short* Wt = (unsigned short*)alloc((size_t)HID * HID * 2);
    unsigned short* hs = (unsigned short*)alloc((size_t)N * HID * 2);

    init_counts<<<(N + 255) / 256, 256, 0, stream>>>(cnt, fill, N);
    count_deg<<<(E + 255) / 256, 256, 0, stream>>>(dst, cnt, E);
    const int nb = (N + 1023) / 1024;
    scan1<<<nb, 1024, 0, stream>>>(cnt, rowstart, bsum, N);
    scan2<<<1, 64, 0, stream>>>(bsum, nb);
    scan3<<<(N + 255) / 256, 256, 0, stream>>>(rowstart, bsum, cnt, dinv, N);
    csr_fill<<<(E + 255) / 256, 256, 0, stream>>>(src, dst, rowstart, fill, csr, E);
    w_transpose<<<(HID * HID) / 256, 256, 0, stream>>>(W, Wt);
    dim3 gg((N + BM - 1) / BM, HID / BN);
    gemm_xw<<<gg, 256, 0, stream>>>(X, Wt, dinv, hs, N);
    agg_ln<<<(N + 3) / 4, 256, 0, stream>>>(hs, X, b, gamma, beta, rowstart, cnt, dinv, csr, out, N);
}

// Round 3
// 485.463 us; speedup vs baseline: 1.0741x; 1.0741x over previous
//
#include <hip/hip_runtime.h>

#define HID 512

typedef unsigned int uint32;
using bf16x8 = __attribute__((ext_vector_type(8))) short;
using f32x4  = __attribute__((ext_vector_type(4))) float;
typedef __attribute__((ext_vector_type(8))) unsigned short ushort8v;

__device__ __forceinline__ unsigned short f2bf(float f) {
    uint32 u = __float_as_uint(f);
    uint32 r = (u + 0x7FFFu + ((u >> 16) & 1u)) >> 16;   // RNE
    return (unsigned short)r;
}
__device__ __forceinline__ float bf2f(unsigned short u) {
    return __uint_as_float(((uint32)u) << 16);
}

// async global->LDS, 16B per lane; LDS dest is wave-uniform base + lane*16
__device__ __forceinline__ void gl_lds16(const unsigned short* g, unsigned short* l) {
    __builtin_amdgcn_global_load_lds(
        (const __attribute__((address_space(1))) void*)g,
        (__attribute__((address_space(3))) void*)l,
        16, 0, 0);
}

// ---------------- counters init ----------------
__global__ void init_counts(int* cnt, int* fill, int n) {
    int i = blockIdx.x * 256 + threadIdx.x;
    if (i < n) { cnt[i] = 0; fill[i] = 0; }
}

// ---------------- in-degree count (dst only) ----------------
__global__ void count_deg(const int* __restrict__ dst, int* __restrict__ cnt, int e) {
    int i = blockIdx.x * 256 + threadIdx.x;
    if (i < e) atomicAdd(&cnt[dst[i]], 1);
}

// ---------------- 3-phase exclusive scan ----------------
__global__ __launch_bounds__(1024) void scan1(const int* __restrict__ cnt,
                                              int* __restrict__ rowstart,
                                              int* __restrict__ bsum, int n) {
    __shared__ int sh[1024];
    int i = blockIdx.x * 1024 + threadIdx.x;
    int x = (i < n) ? cnt[i] : 0;
    sh[threadIdx.x] = x;
    __syncthreads();
    for (int off = 1; off < 1024; off <<= 1) {
        int y = 0;
        if ((int)threadIdx.x >= off) y = sh[threadIdx.x - off];
        __syncthreads();
        sh[threadIdx.x] += y;
        __syncthreads();
    }
    if (i < n) rowstart[i] = sh[threadIdx.x] - x;   // exclusive
    if (threadIdx.x == 1023) bsum[blockIdx.x] = sh[1023];
}

__global__ void scan2(int* bsum, int nb) {
    if (threadIdx.x == 0 && blockIdx.x == 0) {
        int run = 0;
        for (int i = 0; i < nb; ++i) { int v = bsum[i]; bsum[i] = run; run += v; }
    }
}

__global__ void scan3(int* __restrict__ rowstart, const int* __restrict__ bsum,
                      const int* __restrict__ cnt, float* __restrict__ dinv, int n) {
    int i = blockIdx.x * 256 + threadIdx.x;
    if (i < n) {
        rowstart[i] += bsum[i >> 10];
        dinv[i] = rsqrtf((float)(cnt[i] + 1));   // +1 self loop
    }
}

// ---------------- CSR fill ----------------
__global__ void csr_fill(const int* __restrict__ src, const int* __restrict__ dst,
                         const int* __restrict__ rowstart, int* __restrict__ fill,
                         int* __restrict__ csr, int e) {
    int i = blockIdx.x * 256 + threadIdx.x;
    if (i < e) {
        int d = dst[i];
        int p = atomicAdd(&fill[d], 1);
        csr[rowstart[d] + p] = src[i];
    }
}

// ---------------- W transpose + bf16: Wt[n][k] = bf16(W[k][n]) ----------------
__global__ void w_transpose(const float* __restrict__ W, unsigned short* __restrict__ Wt) {
    int idx = blockIdx.x * 256 + threadIdx.x;
    if (idx < HID * HID) {
        int k = idx >> 9, n = idx & (HID - 1);
        Wt[n * HID + k] = f2bf(W[k * HID + n]);
    }
}

// ---------------- X -> bf16 (pad rows zeroed) ----------------
__global__ void x_to_bf16(const float* __restrict__ X, unsigned short* __restrict__ Xbf,
                          int n_elems, int pad_elems) {
    int base = (blockIdx.x * 256 + threadIdx.x) * 8;
    if (base < n_elems) {
        f32x4 a = *(const f32x4*)(X + base);
        f32x4 b = *(const f32x4*)(X + base + 4);
        ushort8v w;
        w[0] = f2bf(a[0]); w[1] = f2bf(a[1]); w[2] = f2bf(a[2]); w[3] = f2bf(a[3]);
        w[4] = f2bf(b[0]); w[5] = f2bf(b[1]); w[6] = f2bf(b[2]); w[7] = f2bf(b[3]);
        *(ushort8v*)(Xbf + base) = w;
    } else if (base < pad_elems) {
        ushort8v w = {0, 0, 0, 0, 0, 0, 0, 0};
        *(ushort8v*)(Xbf + base) = w;
    }
}

// ---------------- GEMM (m97 structure): hs = bf16( (Xbf@Wt^T) * dinv[row] ) --------
// grid = (HID/128, M_pad/128); blockIdx.x = col block (fastest -> A-tile L2 reuse)
__global__ __launch_bounds__(256) void gemm_xw(const unsigned short* __restrict__ Xbf,
                                               const unsigned short* __restrict__ Wt,
                                               const float* __restrict__ dinv,
                                               unsigned short* __restrict__ hs) {
    __shared__ unsigned short Alds[128 * 32];
    __shared__ unsigned short Blds[128 * 32];
    const int t = threadIdx.x;
    const int lane = t & 63, wid = t >> 6;
    const int wm = wid >> 1, wn = wid & 1;          // 2x2 waves -> 64x64 each
    const int row_base = blockIdx.y * 128;
    const int col_base = blockIdx.x * 128;

    // staging addresses: wave `wid` covers rows [wid*32, wid*32+32) in two 16-row chunks
    const int rchunk = lane >> 2;        // 0..15
    const int kq = (lane & 3) * 8;       // 0,8,16,24 (bf16 elems)
    const unsigned short* gA0 = Xbf + (size_t)(row_base + wid * 32 + rchunk) * HID + kq;
    const unsigned short* gA1 = gA0 + 16 * HID;
    const unsigned short* gB0 = Wt + (size_t)(col_base + wid * 32 + rchunk) * HID + kq;
    const unsigned short* gB1 = gB0 + 16 * HID;
    unsigned short* lA0 = &Alds[(wid * 32) * 32];
    unsigned short* lA1 = &Alds[(wid * 32 + 16) * 32];
    unsigned short* lB0 = &Blds[(wid * 32) * 32];
    unsigned short* lB1 = &Blds[(wid * 32 + 16) * 32];

    f32x4 acc[4][4];
    #pragma unroll
    for (int m = 0; m < 4; ++m)
        #pragma unroll
        for (int n = 0; n < 4; ++n)
            acc[m][n] = (f32x4){0.f, 0.f, 0.f, 0.f};

    const int rr = lane & 15;
    const int kgr = (lane >> 4) * 8;

    for (int k0 = 0; k0 < HID; k0 += 32) {
        gl_lds16(gA0 + k0, lA0);
        gl_lds16(gA1 + k0, lA1);
        gl_lds16(gB0 + k0, lB0);
        gl_lds16(gB1 + k0, lB1);
        __syncthreads();   // drains vmcnt(0): tiles ready

        bf16x8 afr[4], bfr[4];
        #pragma unroll
        for (int m = 0; m < 4; ++m)
            afr[m] = *(const bf16x8*)&Alds[(wm * 64 + m * 16 + rr) * 32 + kgr];
        #pragma unroll
        for (int n = 0; n < 4; ++n)
            bfr[n] = *(const bf16x8*)&Blds[(wn * 64 + n * 16 + rr) * 32 + kgr];
        #pragma unroll
        for (int m = 0; m < 4; ++m)
            #pragma unroll
            for (int n = 0; n < 4; ++n)
                acc[m][n] = __builtin_amdgcn_mfma_f32_16x16x32_bf16(afr[m], bfr[n], acc[m][n], 0, 0, 0);
        __syncthreads();   // protect LDS from next iter's stage
    }

    // epilogue: C/D mapping col = lane&15, row = (lane>>4)*4 + reg
    const int rgrp = (lane >> 4) * 4;
    const int cc = lane & 15;
    #pragma unroll
    for (int m = 0; m < 4; ++m) {
        #pragma unroll
        for (int r = 0; r < 4; ++r) {
            int grow = row_base + wm * 64 + m * 16 + rgrp + r;
            float g = dinv[grow];
            #pragma unroll
            for (int n = 0; n < 4; ++n) {
                int gcol = col_base + wn * 64 + n * 16 + cc;
                hs[(size_t)grow * HID + gcol] = f2bf(acc[m][n][r] * g);
            }
        }
    }
}

// ---------------- fused gather-aggregate + scale + b + residual + LayerNorm --------
__global__ __launch_bounds__(256) void agg_ln(const unsigned short* __restrict__ hs,
                                              const float* __restrict__ resid,
                                              const float* __restrict__ bvec,
                                              const float* __restrict__ gamma,
                                              const float* __restrict__ beta,
                                              const int* __restrict__ rowstart,
                                              const int* __restrict__ cnt,
                                              const float* __restrict__ dinv,
                                              const int* __restrict__ csr,
                                              float* __restrict__ out, int nn) {
    const int wave = threadIdx.x >> 6;
    const int lane = threadIdx.x & 63;
    const int n = blockIdx.x * 4 + wave;
    if (n >= nn) return;
    const int c0 = lane * 8;

    float acc[8];
    {   // self-loop message: hs already includes dinv[src]
        ushort8v v = *(const ushort8v*)(hs + (size_t)n * HID + c0);
        #pragma unroll
        for (int j = 0; j < 8; ++j) acc[j] = bf2f(v[j]);
    }
    const int s0 = rowstart[n];
    const int m = cnt[n];
    const int* idx = csr + s0;
    int i = 0;
    for (; i + 4 <= m; i += 4) {
        int sa = idx[i], sb = idx[i + 1], sc = idx[i + 2], sd = idx[i + 3];
        ushort8v va = *(const ushort8v*)(hs + (size_t)sa * HID + c0);
        ushort8v vb = *(const ushort8v*)(hs + (size_t)sb * HID + c0);
        ushort8v vc = *(const ushort8v*)(hs + (size_t)sc * HID + c0);
        ushort8v vd = *(const ushort8v*)(hs + (size_t)sd * HID + c0);
        #pragma unroll
        for (int j = 0; j < 8; ++j)
            acc[j] += (bf2f(va[j]) + bf2f(vb[j])) + (bf2f(vc[j]) + bf2f(vd[j]));
    }
    for (; i < m; ++i) {
        int s = idx[i];
        ushort8v v = *(const ushort8v*)(hs + (size_t)s * HID + c0);
        #pragma unroll
        for (int j = 0; j < 8; ++j) acc[j] += bf2f(v[j]);
    }

    const float g = dinv[n];
    // non-temporal: streaming residual must not evict hs from L3
    f32x4 r0 = __builtin_nontemporal_load((const f32x4*)(resid + (size_t)n * HID + c0));
    f32x4 r1 = __builtin_nontemporal_load((const f32x4*)(resid + (size_t)n * HID + c0 + 4));
    float val[8];
    #pragma unroll
    for (int j = 0; j < 4; ++j) {
        val[j]     = r0[j] + g * acc[j]     + bvec[c0 + j];
        val[j + 4] = r1[j] + g * acc[j + 4] + bvec[c0 + j + 4];
    }

    float s = 0.f, q = 0.f;
    #pragma unroll
    for (int j = 0; j < 8; ++j) { s += val[j]; q += val[j] * val[j]; }
    #pragma unroll
    for (int off = 32; off > 0; off >>= 1) {
        s += __shfl_xor(s, off, 64);
        q += __shfl_xor(q, off, 64);
    }
    const float mean = s * (1.f / 512.f);
    const float var = q * (1.f / 512.f) - mean * mean;
    const float rstd = rsqrtf(var + 1e-5f);

    f32x4 o0, o1;
    #pragma unroll
    for (int j = 0; j < 4; ++j) {
        o0[j] = (val[j]     - mean) * rstd * gamma[c0 + j]     + beta[c0 + j];
        o1[j] = (val[j + 4] - mean) * rstd * gamma[c0 + j + 4] + beta[c0 + j + 4];
    }
    // non-temporal store: out is never re-read
    __builtin_nontemporal_store(o0, (f32x4*)(out + (size_t)n * HID + c0));
    __builtin_nontemporal_store(o1, (f32x4*)(out + (size_t)n * HID + c0 + 4));
}

extern "C" void kernel_launch(void* const* d_in, const int* in_sizes, int n_in,
                              void* d_out, int out_size, void* d_ws, size_t ws_size,
                              hipStream_t stream) {
    const float* X     = (const float*)d_in[0];   // label_emb [N][512], also residual
    const int*   edges = (const int*)d_in[1];     // [2][E]
    const float* W     = (const float*)d_in[2];   // [512][512]
    const float* b     = (const float*)d_in[3];
    const float* gamma = (const float*)d_in[4];
    const float* beta  = (const float*)d_in[5];
    float* out = (float*)d_out;

    const int E = in_sizes[1] / 2;
    const int N = in_sizes[0] / HID;
    const int M_pad = ((N + 127) / 128) * 128;
    const int* src = edges;
    const int* dst = edges + E;

    // workspace layout
    char* w = (char*)d_ws;
    auto alloc = [&](size_t bytes) { char* p = w; w += (bytes + 255) & ~(size_t)255; return p; };
    int*   cnt      = (int*)alloc((size_t)N * 4);
    int*   fill     = (int*)alloc((size_t)N * 4);
    int*   rowstart = (int*)alloc((size_t)N * 4);
    int*   bsum     = (int*)alloc(256 * 4);
    float* dinv     = (float*)alloc((size_t)M_pad * 4);
    int*   csr      = (int*)alloc((size_t)E * 4);
    unsigned short* Wt = (unsigned short*)alloc((size_t)HID * HID * 2);
    unsigned short* hs = (unsigned short*)alloc((size_t)M_pad * HID * 2);
    // Xbf lives in d_out (free until agg_ln, which only reads hs/resid/csr)
    unsigned short* Xbf = (unsigned short*)d_out;

    init_counts<<<(N + 255) / 256, 256, 0, stream>>>(cnt, fill, N);
    count_deg<<<(E + 255) / 256, 256, 0, stream>>>(dst, cnt, E);
    const int nb = (N + 1023) / 1024;
    scan1<<<nb, 1024, 0, stream>>>(cnt, rowstart, bsum, N);
    scan2<<<1, 64, 0, stream>>>(bsum, nb);
    scan3<<<(N + 255) / 256, 256, 0, stream>>>(rowstart, bsum, cnt, dinv, N);
    csr_fill<<<(E + 255) / 256, 256, 0, stream>>>(src, dst, rowstart, fill, csr, E);
    w_transpose<<<(HID * HID) / 256, 256, 0, stream>>>(W, Wt);
    const int pad_elems = M_pad * HID;
    x_to_bf16<<<(pad_elems / 8 + 255) / 256, 256, 0, stream>>>(X, Xbf, N * HID, pad_elems);
    dim3 gg(HID / 128, M_pad / 128);
    gemm_xw<<<gg, 256, 0, stream>>>(Xbf, Wt, dinv, hs);
    agg_ln<<<(N + 3) / 4, 256, 0, stream>>>(hs, X, b, gamma, beta, rowstart, cnt, dinv, csr, out, N);
}

// Round 6
// 471.275 us; speedup vs baseline: 1.1064x; 1.0301x over previous
//
#include <hip/hip_runtime.h>

#define HID 512

typedef unsigned int uint32;
using bf16x8 = __attribute__((ext_vector_type(8))) short;
using f32x4  = __attribute__((ext_vector_type(4))) float;
using f32x2  = __attribute__((ext_vector_type(2))) float;
using u16x4  = __attribute__((ext_vector_type(4))) unsigned short;

__device__ __forceinline__ unsigned short f2bf(float f) {
    uint32 u = __float_as_uint(f);
    uint32 r = (u + 0x7FFFu + ((u >> 16) & 1u)) >> 16;   // RNE
    return (unsigned short)r;
}
__device__ __forceinline__ float bf2f(unsigned short u) {
    return __uint_as_float(((uint32)u) << 16);
}

// async global->LDS, 16B per lane; LDS dest is wave-uniform base + lane*16
__device__ __forceinline__ void gl_lds16(const unsigned short* g, unsigned short* l) {
    __builtin_amdgcn_global_load_lds(
        (const __attribute__((address_space(1))) void*)g,
        (__attribute__((address_space(3))) void*)l,
        16, 0, 0);
}

// ---------------- counters init ----------------
__global__ void init_counts(int* cnt, int* fill, int n) {
    int i = blockIdx.x * 256 + threadIdx.x;
    if (i < n) { cnt[i] = 0; fill[i] = 0; }
}

// ---------------- in-degree count (dst only) ----------------
__global__ void count_deg(const int* __restrict__ dst, int* __restrict__ cnt, int e) {
    int i = blockIdx.x * 256 + threadIdx.x;
    if (i < e) atomicAdd(&cnt[dst[i]], 1);
}

// ---------------- 3-phase exclusive scan ----------------
__global__ __launch_bounds__(1024) void scan1(const int* __restrict__ cnt,
                                              int* __restrict__ rowstart,
                                              int* __restrict__ bsum, int n) {
    __shared__ int sh[1024];
    int i = blockIdx.x * 1024 + threadIdx.x;
    int x = (i < n) ? cnt[i] : 0;
    sh[threadIdx.x] = x;
    __syncthreads();
    for (int off = 1; off < 1024; off <<= 1) {
        int y = 0;
        if ((int)threadIdx.x >= off) y = sh[threadIdx.x - off];
        __syncthreads();
        sh[threadIdx.x] += y;
        __syncthreads();
    }
    if (i < n) rowstart[i] = sh[threadIdx.x] - x;   // exclusive
    if (threadIdx.x == 1023) bsum[blockIdx.x] = sh[1023];
}

__global__ void scan2(int* bsum, int nb) {
    if (threadIdx.x == 0 && blockIdx.x == 0) {
        int run = 0;
        for (int i = 0; i < nb; ++i) { int v = bsum[i]; bsum[i] = run; run += v; }
    }
}

__global__ void scan3(int* __restrict__ rowstart, const int* __restrict__ bsum,
                      const int* __restrict__ cnt, float* __restrict__ dinv, int n) {
    int i = blockIdx.x * 256 + threadIdx.x;
    if (i < n) {
        rowstart[i] += bsum[i >> 10];
        dinv[i] = rsqrtf((float)(cnt[i] + 1));   // +1 self loop
    }
}

// ---------------- CSR fill ----------------
__global__ void csr_fill(const int* __restrict__ src, const int* __restrict__ dst,
                         const int* __restrict__ rowstart, int* __restrict__ fill,
                         int* __restrict__ csr, int e) {
    int i = blockIdx.x * 256 + threadIdx.x;
    if (i < e) {
        int d = dst[i];
        int p = atomicAdd(&fill[d], 1);
        csr[rowstart[d] + p] = src[i];
    }
}

// ---------------- W transpose + bf16: Wt[n][k] = bf16(W[k][n]) ----------------
__global__ void w_transpose(const float* __restrict__ W, unsigned short* __restrict__ Wt) {
    int idx = blockIdx.x * 256 + threadIdx.x;
    if (idx < HID * HID) {
        int k = idx >> 9, n = idx & (HID - 1);
        Wt[n * HID + k] = f2bf(W[k * HID + n]);
    }
}

// ---------------- X -> bf16 (pad rows zeroed) ----------------
__global__ void x_to_bf16(const float* __restrict__ X, unsigned short* __restrict__ Xbf,
                          int n_elems, int pad_elems) {
    int base = (blockIdx.x * 256 + threadIdx.x) * 8;
    if (base < n_elems) {
        f32x4 a = *(const f32x4*)(X + base);
        f32x4 b = *(const f32x4*)(X + base + 4);
        u16x4 w0, w1;
        w0[0] = f2bf(a[0]); w0[1] = f2bf(a[1]); w0[2] = f2bf(a[2]); w0[3] = f2bf(a[3]);
        w1[0] = f2bf(b[0]); w1[1] = f2bf(b[1]); w1[2] = f2bf(b[2]); w1[3] = f2bf(b[3]);
        *(u16x4*)(Xbf + base) = w0;
        *(u16x4*)(Xbf + base + 4) = w1;
    } else if (base < pad_elems) {
        u16x4 z = {0, 0, 0, 0};
        *(u16x4*)(Xbf + base) = z;
        *(u16x4*)(Xbf + base + 4) = z;
    }
}

// ---------------- GEMM: hs = bf16( (Xbf@Wt^T) * dinv[row] ) --------
// 1D grid, XCD-chunked swizzle (nwg % 8 == 0 GUARANTEED: M_pad % 256 == 0);
// BK=64; XOR-swizzled LDS via pre-swizzled global src (rule #21).
#define NWGX 4   // HID/128 col blocks
__global__ __launch_bounds__(256) void gemm_xw(const unsigned short* __restrict__ Xbf,
                                               const unsigned short* __restrict__ Wt,
                                               const float* __restrict__ dinv,
                                               unsigned short* __restrict__ hs,
                                               int nwg) {
    __shared__ unsigned short Alds[128 * 64];
    __shared__ unsigned short Blds[128 * 64];
    // XCD-chunked bijective swizzle (requires nwg % 8 == 0)
    const int cpx = nwg >> 3;
    const int swz = (blockIdx.x & 7) * cpx + (blockIdx.x >> 3);
    const int row_base = (swz >> 2) * 128;      // col-fastest -> A-tile reuse in XCD L2
    const int col_base = (swz & 3) * 128;

    const int t = threadIdx.x;
    const int lane = t & 63, wid = t >> 6;
    const int wm = wid >> 1, wn = wid & 1;      // 2x2 waves -> 64x64 each

    // staging: per gl_lds round, wave covers 8 rows x 64 cols (1KB LDS contiguous).
    // LDS[row][c] = G[row][c ^ (row&7)]  (row&7 == lane>>3 here), chunks of 8 bf16.
    const int srow = lane >> 3;                       // 0..7, == row&7 for this call
    const int gch  = ((lane & 7) ^ srow) * 8;         // pre-swizzled global chunk
    const unsigned short* gA = Xbf + (size_t)(row_base + wid * 8 + srow) * HID + gch;
    const unsigned short* gB = Wt  + (size_t)(col_base + wid * 8 + srow) * HID + gch;
    unsigned short* lA = &Alds[wid * 512];            // 8 rows * 64
    unsigned short* lB = &Blds[wid * 512];

    f32x4 acc[4][4];
    #pragma unroll
    for (int m = 0; m < 4; ++m)
        #pragma unroll
        for (int n = 0; n < 4; ++n)
            acc[m][n] = (f32x4){0.f, 0.f, 0.f, 0.f};

    const int rr = lane & 15;
    const int kg8 = lane >> 4;     // 0..3: which 8-elem chunk within 32-k slice

    for (int k0 = 0; k0 < HID; k0 += 64) {
        #pragma unroll
        for (int rd = 0; rd < 4; ++rd) {
            gl_lds16(gA + (size_t)rd * 32 * HID + k0, lA + rd * 2048);
            gl_lds16(gB + (size_t)rd * 32 * HID + k0, lB + rd * 2048);
        }
        __syncthreads();

        bf16x8 afr[4][2], bfr[4][2];
        #pragma unroll
        for (int m = 0; m < 4; ++m) {
            int row = wm * 64 + m * 16 + rr;
            #pragma unroll
            for (int ks = 0; ks < 2; ++ks)
                afr[m][ks] = *(const bf16x8*)&Alds[row * 64 + (((ks * 4 + kg8) ^ (row & 7)) * 8)];
        }
        #pragma unroll
        for (int n = 0; n < 4; ++n) {
            int row = wn * 64 + n * 16 + rr;
            #pragma unroll
            for (int ks = 0; ks < 2; ++ks)
                bfr[n][ks] = *(const bf16x8*)&Blds[row * 64 + (((ks * 4 + kg8) ^ (row & 7)) * 8)];
        }
        #pragma unroll
        for (int ks = 0; ks < 2; ++ks)
            #pragma unroll
            for (int m = 0; m < 4; ++m)
                #pragma unroll
                for (int n = 0; n < 4; ++n)
                    acc[m][n] = __builtin_amdgcn_mfma_f32_16x16x32_bf16(afr[m][ks], bfr[n][ks], acc[m][n], 0, 0, 0);
        __syncthreads();
    }

    // epilogue: C/D mapping col = lane&15, row = (lane>>4)*4 + reg; write bf16
    const int rgrp = (lane >> 4) * 4;
    const int cc = lane & 15;
    #pragma unroll
    for (int m = 0; m < 4; ++m) {
        #pragma unroll
        for (int r = 0; r < 4; ++r) {
            int grow = row_base + wm * 64 + m * 16 + rgrp + r;
            float g = dinv[grow];
            #pragma unroll
            for (int n = 0; n < 4; ++n) {
                int gcol = col_base + wn * 64 + n * 16 + cc;
                hs[(size_t)grow * HID + gcol] = f2bf(acc[m][n][r] * g);
            }
        }
    }
}

// ---------------- pass A: gather cols [0,256) + resid + b -> valA bf16, partial stats ---
__global__ __launch_bounds__(256) void agg_half0(const unsigned short* __restrict__ hs,
                                                 const float* __restrict__ resid,
                                                 const float* __restrict__ bvec,
                                                 const int* __restrict__ rowstart,
                                                 const int* __restrict__ cnt,
                                                 const float* __restrict__ dinv,
                                                 const int* __restrict__ csr,
                                                 unsigned short* __restrict__ valA,
                                                 f32x2* __restrict__ sqA, int nn) {
    const int wave = threadIdx.x >> 6;
    const int lane = threadIdx.x & 63;
    const int n = blockIdx.x * 4 + wave;
    if (n >= nn) return;
    const int c = lane * 4;                    // col in [0,256)

    float acc[4];
    {   // self-loop message (hs already includes dinv[src])
        u16x4 v = *(const u16x4*)(hs + (size_t)n * HID + c);
        #pragma unroll
        for (int j = 0; j < 4; ++j) acc[j] = bf2f(v[j]);
    }
    const int m = cnt[n];
    const int* idx = csr + rowstart[n];
    int i = 0;
    for (; i + 4 <= m; i += 4) {
        int sa = idx[i], sb = idx[i + 1], sc = idx[i + 2], sd = idx[i + 3];
        u16x4 va = *(const u16x4*)(hs + (size_t)sa * HID + c);
        u16x4 vb = *(const u16x4*)(hs + (size_t)sb * HID + c);
        u16x4 vc = *(const u16x4*)(hs + (size_t)sc * HID + c);
        u16x4 vd = *(const u16x4*)(hs + (size_t)sd * HID + c);
        #pragma unroll
        for (int j = 0; j < 4; ++j)
            acc[j] += (bf2f(va[j]) + bf2f(vb[j])) + (bf2f(vc[j]) + bf2f(vd[j]));
    }
    for (; i < m; ++i) {
        u16x4 v = *(const u16x4*)(hs + (size_t)idx[i] * HID + c);
        #pragma unroll
        for (int j = 0; j < 4; ++j) acc[j] += bf2f(v[j]);
    }

    const float g = dinv[n];
    f32x4 r = __builtin_nontemporal_load((const f32x4*)(resid + (size_t)n * HID + c));
    float val[4];
    float s = 0.f, q = 0.f;
    #pragma unroll
    for (int j = 0; j < 4; ++j) {
        val[j] = r[j] + g * acc[j] + bvec[c + j];
        s += val[j]; q += val[j] * val[j];
    }
    #pragma unroll
    for (int off = 32; off > 0; off >>= 1) {
        s += __shfl_xor(s, off, 64);
        q += __shfl_xor(q, off, 64);
    }
    u16x4 w;
    #pragma unroll
    for (int j = 0; j < 4; ++j) w[j] = f2bf(val[j]);
    *(u16x4*)(valA + (size_t)n * 256 + c) = w;
    if (lane == 0) sqA[n] = (f32x2){s, q};
}

// ---------------- pass B: gather cols [256,512) + stats merge + fused LayerNorm -------
__global__ __launch_bounds__(256) void agg_half1_ln(const unsigned short* __restrict__ hs,
                                                    const float* __restrict__ resid,
                                                    const float* __restrict__ bvec,
                                                    const float* __restrict__ gamma,
                                                    const float* __restrict__ beta,
                                                    const int* __restrict__ rowstart,
                                                    const int* __restrict__ cnt,
                                                    const float* __restrict__ dinv,
                                                    const int* __restrict__ csr,
                                                    const unsigned short* __restrict__ valA,
                                                    const f32x2* __restrict__ sqA,
                                                    float* __restrict__ out, int nn) {
    const int wave = threadIdx.x >> 6;
    const int lane = threadIdx.x & 63;
    const int n = blockIdx.x * 4 + wave;
    if (n >= nn) return;
    const int c = 256 + lane * 4;              // col in [256,512)

    float acc[4];
    {
        u16x4 v = *(const u16x4*)(hs + (size_t)n * HID + c);
        #pragma unroll
        for (int j = 0; j < 4; ++j) acc[j] = bf2f(v[j]);
    }
    const int m = cnt[n];
    const int* idx = csr + rowstart[n];
    int i = 0;
    for (; i + 4 <= m; i += 4) {
        int sa = idx[i], sb = idx[i + 1], sc = idx[i + 2], sd = idx[i + 3];
        u16x4 va = *(const u16x4*)(hs + (size_t)sa * HID + c);
        u16x4 vb = *(const u16x4*)(hs + (size_t)sb * HID + c);
        u16x4 vc = *(const u16x4*)(hs + (size_t)sc * HID + c);
        u16x4 vd = *(const u16x4*)(hs + (size_t)sd * HID + c);
        #pragma unroll
        for (int j = 0; j < 4; ++j)
            acc[j] += (bf2f(va[j]) + bf2f(vb[j])) + (bf2f(vc[j]) + bf2f(vd[j]));
    }
    for (; i < m; ++i) {
        u16x4 v = *(const u16x4*)(hs + (size_t)idx[i] * HID + c);
        #pragma unroll
        for (int j = 0; j < 4; ++j) acc[j] += bf2f(v[j]);
    }

    const float g = dinv[n];
    f32x4 r = __builtin_nontemporal_load((const f32x4*)(resid + (size_t)n * HID + c));
    float val[4];
    float s = 0.f, q = 0.f;
    #pragma unroll
    for (int j = 0; j < 4; ++j) {
        val[j] = r[j] + g * acc[j] + bvec[c + j];
        s += val[j]; q += val[j] * val[j];
    }
    #pragma unroll
    for (int off = 32; off > 0; off >>= 1) {
        s += __shfl_xor(s, off, 64);
        q += __shfl_xor(q, off, 64);
    }
    f32x2 pa = sqA[n];
    s += pa[0]; q += pa[1];
    const float mean = s * (1.f / 512.f);
    const float var = q * (1.f / 512.f) - mean * mean;
    const float rstd = rsqrtf(var + 1e-5f);

    // normalize half B (in registers)
    f32x4 ob;
    #pragma unroll
    for (int j = 0; j < 4; ++j)
        ob[j] = (val[j] - mean) * rstd * gamma[c + j] + beta[c + j];
    __builtin_nontemporal_store(ob, (f32x4*)(out + (size_t)n * HID + c));

    // normalize half A (re-read bf16 valA)
    const int ca = lane * 4;
    u16x4 wa = *(const u16x4*)(valA + (size_t)n * 256 + ca);
    f32x4 oa;
    #pragma unroll
    for (int j = 0; j < 4; ++j)
        oa[j] = (bf2f(wa[j]) - mean) * rstd * gamma[ca + j] + beta[ca + j];
    __builtin_nontemporal_store(oa, (f32x4*)(out + (size_t)n * HID + ca));
}

extern "C" void kernel_launch(void* const* d_in, const int* in_sizes, int n_in,
                              void* d_out, int out_size, void* d_ws, size_t ws_size,
                              hipStream_t stream) {
    const float* X     = (const float*)d_in[0];   // label_emb [N][512], also residual
    const int*   edges = (const int*)d_in[1];     // [2][E]
    const float* W     = (const float*)d_in[2];   // [512][512]
    const float* b     = (const float*)d_in[3];
    const float* gamma = (const float*)d_in[4];
    const float* beta  = (const float*)d_in[5];
    float* out = (float*)d_out;

    const int E = in_sizes[1] / 2;
    const int N = in_sizes[0] / HID;
    // M_pad multiple of 256 -> nwg = (M_pad/128)*4 divisible by 8 -> bijective XCD swizzle
    const int M_pad = ((N + 255) / 256) * 256;
    const int* src = edges;
    const int* dst = edges + E;

    // workspace layout
    char* w = (char*)d_ws;
    auto alloc = [&](size_t bytes) { char* p = w; w += (bytes + 255) & ~(size_t)255; return p; };
    int*   cnt      = (int*)alloc((size_t)N * 4);
    int*   fill     = (int*)alloc((size_t)N * 4);
    int*   rowstart = (int*)alloc((size_t)N * 4);
    int*   bsum     = (int*)alloc(256 * 4);
    float* dinv     = (float*)alloc((size_t)M_pad * 4);
    int*   csr      = (int*)alloc((size_t)E * 4);
    unsigned short* Wt = (unsigned short*)alloc((size_t)HID * HID * 2);
    unsigned short* hs = (unsigned short*)alloc((size_t)M_pad * HID * 2);
    unsigned short* valA = (unsigned short*)alloc((size_t)N * 256 * 2);
    f32x2* sqA = (f32x2*)alloc((size_t)N * 8);
    // Xbf lives in d_out (free until pass B; GEMM consumed it by then)
    unsigned short* Xbf = (unsigned short*)d_out;

    init_counts<<<(N + 255) / 256, 256, 0, stream>>>(cnt, fill, N);
    count_deg<<<(E + 255) / 256, 256, 0, stream>>>(dst, cnt, E);
    const int nb = (N + 1023) / 1024;
    scan1<<<nb, 1024, 0, stream>>>(cnt, rowstart, bsum, N);
    scan2<<<1, 64, 0, stream>>>(bsum, nb);
    scan3<<<(N + 255) / 256, 256, 0, stream>>>(rowstart, bsum, cnt, dinv, N);
    csr_fill<<<(E + 255) / 256, 256, 0, stream>>>(src, dst, rowstart, fill, csr, E);
    w_transpose<<<(HID * HID) / 256, 256, 0, stream>>>(W, Wt);
    const int pad_elems = M_pad * HID;
    x_to_bf16<<<(pad_elems / 8 + 255) / 256, 256, 0, stream>>>(X, Xbf, N * HID, pad_elems);
    const int nwg = (M_pad / 128) * NWGX;   // divisible by 8
    gemm_xw<<<nwg, 256, 0, stream>>>(Xbf, Wt, dinv, hs, nwg);
    agg_half0<<<(N + 3) / 4, 256, 0, stream>>>(hs, X, b, rowstart, cnt, dinv, csr, valA, sqA, N);
    agg_half1_ln<<<(N + 3) / 4, 256, 0, stream>>>(hs, X, b, gamma, beta, rowstart, cnt, dinv, csr, valA, sqA, out, N);
}

// Round 7
// 363.590 us; speedup vs baseline: 1.4341x; 1.2962x over previous
//
#include <hip/hip_runtime.h>

#define HID 512

typedef unsigned int uint32;
using bf16x8 = __attribute__((ext_vector_type(8))) short;
using f32x4  = __attribute__((ext_vector_type(4))) float;
using f32x2  = __attribute__((ext_vector_type(2))) float;
using u32x2  = __attribute__((ext_vector_type(2))) unsigned int;
using u16x4  = __attribute__((ext_vector_type(4))) unsigned short;

__device__ __forceinline__ unsigned short f2bf(float f) {
    uint32 u = __float_as_uint(f);
    uint32 r = (u + 0x7FFFu + ((u >> 16) & 1u)) >> 16;   // RNE
    return (unsigned short)r;
}
__device__ __forceinline__ float bf2f(unsigned short u) {
    return __uint_as_float(((uint32)u) << 16);
}

// async global->LDS, 16B per lane; LDS dest is wave-uniform base + lane*16
__device__ __forceinline__ void gl_lds16(const unsigned short* g, unsigned short* l) {
    __builtin_amdgcn_global_load_lds(
        (const __attribute__((address_space(1))) void*)g,
        (__attribute__((address_space(3))) void*)l,
        16, 0, 0);
}

// ---------------- counters init ----------------
__global__ void init_counts(int* cnt, int* fill, int n) {
    int i = blockIdx.x * 256 + threadIdx.x;
    if (i < n) { cnt[i] = 0; fill[i] = 0; }
}

// ---------------- in-degree count (dst only) ----------------
__global__ void count_deg(const int* __restrict__ dst, int* __restrict__ cnt, int e) {
    int i = blockIdx.x * 256 + threadIdx.x;
    if (i < e) atomicAdd(&cnt[dst[i]], 1);
}

// ---------------- 3-phase exclusive scan ----------------
__global__ __launch_bounds__(1024) void scan1(const int* __restrict__ cnt,
                                              int* __restrict__ rowstart,
                                              int* __restrict__ bsum, int n) {
    __shared__ int sh[1024];
    int i = blockIdx.x * 1024 + threadIdx.x;
    int x = (i < n) ? cnt[i] : 0;
    sh[threadIdx.x] = x;
    __syncthreads();
    for (int off = 1; off < 1024; off <<= 1) {
        int y = 0;
        if ((int)threadIdx.x >= off) y = sh[threadIdx.x - off];
        __syncthreads();
        sh[threadIdx.x] += y;
        __syncthreads();
    }
    if (i < n) rowstart[i] = sh[threadIdx.x] - x;   // exclusive
    if (threadIdx.x == 1023) bsum[blockIdx.x] = sh[1023];
}

__global__ void scan2(int* bsum, int nb) {
    if (threadIdx.x == 0 && blockIdx.x == 0) {
        int run = 0;
        for (int i = 0; i < nb; ++i) { int v = bsum[i]; bsum[i] = run; run += v; }
    }
}

__global__ void scan3(int* __restrict__ rowstart, const int* __restrict__ bsum,
                      const int* __restrict__ cnt, float* __restrict__ dinv, int n) {
    int i = blockIdx.x * 256 + threadIdx.x;
    if (i < n) {
        rowstart[i] += bsum[i >> 10];
        dinv[i] = rsqrtf((float)(cnt[i] + 1));   // +1 self loop
    }
}

// ---------------- CSR fill ----------------
__global__ void csr_fill(const int* __restrict__ src, const int* __restrict__ dst,
                         const int* __restrict__ rowstart, int* __restrict__ fill,
                         int* __restrict__ csr, int e) {
    int i = blockIdx.x * 256 + threadIdx.x;
    if (i < e) {
        int d = dst[i];
        int p = atomicAdd(&fill[d], 1);
        csr[rowstart[d] + p] = src[i];
    }
}

// ---------------- W transpose + bf16: Wt[n][k] = bf16(W[k][n]) ----------------
__global__ void w_transpose(const float* __restrict__ W, unsigned short* __restrict__ Wt) {
    int idx = blockIdx.x * 256 + threadIdx.x;
    if (idx < HID * HID) {
        int k = idx >> 9, n = idx & (HID - 1);
        Wt[n * HID + k] = f2bf(W[k * HID + n]);
    }
}

// ---------------- X -> bf16 (pad rows zeroed) ----------------
__global__ void x_to_bf16(const float* __restrict__ X, unsigned short* __restrict__ Xbf,
                          int n_elems, int pad_elems) {
    int base = (blockIdx.x * 256 + threadIdx.x) * 8;
    if (base < n_elems) {
        f32x4 a = *(const f32x4*)(X + base);
        f32x4 b = *(const f32x4*)(X + base + 4);
        u16x4 w0, w1;
        w0[0] = f2bf(a[0]); w0[1] = f2bf(a[1]); w0[2] = f2bf(a[2]); w0[3] = f2bf(a[3]);
        w1[0] = f2bf(b[0]); w1[1] = f2bf(b[1]); w1[2] = f2bf(b[2]); w1[3] = f2bf(b[3]);
        *(u16x4*)(Xbf + base) = w0;
        *(u16x4*)(Xbf + base + 4) = w1;
    } else if (base < pad_elems) {
        u16x4 z = {0, 0, 0, 0};
        *(u16x4*)(Xbf + base) = z;
        *(u16x4*)(Xbf + base + 4) = z;
    }
}

// ---------------- GEMM: hs8 = fp8_e4m3( (Xbf@Wt^T) * dinv[row] ) --------
// 1D grid, XCD-chunked swizzle (nwg % 8 == 0 GUARANTEED: M_pad % 256 == 0);
// BK=64; XOR-swizzled LDS via pre-swizzled global src (rule #21).
#define NWGX 4   // HID/128 col blocks
__global__ __launch_bounds__(256) void gemm_xw(const unsigned short* __restrict__ Xbf,
                                               const unsigned short* __restrict__ Wt,
                                               const float* __restrict__ dinv,
                                               unsigned char* __restrict__ hs8,
                                               int nwg) {
    __shared__ unsigned short Alds[128 * 64];
    __shared__ unsigned short Blds[128 * 64];
    // XCD-chunked bijective swizzle (requires nwg % 8 == 0)
    const int cpx = nwg >> 3;
    const int swz = (blockIdx.x & 7) * cpx + (blockIdx.x >> 3);
    const int row_base = (swz >> 2) * 128;      // col-fastest -> A-tile reuse in XCD L2
    const int col_base = (swz & 3) * 128;

    const int t = threadIdx.x;
    const int lane = t & 63, wid = t >> 6;
    const int wm = wid >> 1, wn = wid & 1;      // 2x2 waves -> 64x64 each

    // staging: per gl_lds round, wave covers 8 rows x 64 cols (1KB LDS contiguous).
    // LDS[row][c] = G[row][c ^ (row&7)]  (row&7 == lane>>3 here), chunks of 8 bf16.
    const int srow = lane >> 3;                       // 0..7, == row&7 for this call
    const int gch  = ((lane & 7) ^ srow) * 8;         // pre-swizzled global chunk
    const unsigned short* gA = Xbf + (size_t)(row_base + wid * 8 + srow) * HID + gch;
    const unsigned short* gB = Wt  + (size_t)(col_base + wid * 8 + srow) * HID + gch;
    unsigned short* lA = &Alds[wid * 512];            // 8 rows * 64
    unsigned short* lB = &Blds[wid * 512];

    f32x4 acc[4][4];
    #pragma unroll
    for (int m = 0; m < 4; ++m)
        #pragma unroll
        for (int n = 0; n < 4; ++n)
            acc[m][n] = (f32x4){0.f, 0.f, 0.f, 0.f};

    const int rr = lane & 15;
    const int kg8 = lane >> 4;     // 0..3: which 8-elem chunk within 32-k slice

    for (int k0 = 0; k0 < HID; k0 += 64) {
        #pragma unroll
        for (int rd = 0; rd < 4; ++rd) {
            gl_lds16(gA + (size_t)rd * 32 * HID + k0, lA + rd * 2048);
            gl_lds16(gB + (size_t)rd * 32 * HID + k0, lB + rd * 2048);
        }
        __syncthreads();

        bf16x8 afr[4][2], bfr[4][2];
        #pragma unroll
        for (int m = 0; m < 4; ++m) {
            int row = wm * 64 + m * 16 + rr;
            #pragma unroll
            for (int ks = 0; ks < 2; ++ks)
                afr[m][ks] = *(const bf16x8*)&Alds[row * 64 + (((ks * 4 + kg8) ^ (row & 7)) * 8)];
        }
        #pragma unroll
        for (int n = 0; n < 4; ++n) {
            int row = wn * 64 + n * 16 + rr;
            #pragma unroll
            for (int ks = 0; ks < 2; ++ks)
                bfr[n][ks] = *(const bf16x8*)&Blds[row * 64 + (((ks * 4 + kg8) ^ (row & 7)) * 8)];
        }
        #pragma unroll
        for (int ks = 0; ks < 2; ++ks)
            #pragma unroll
            for (int m = 0; m < 4; ++m)
                #pragma unroll
                for (int n = 0; n < 4; ++n)
                    acc[m][n] = __builtin_amdgcn_mfma_f32_16x16x32_bf16(afr[m][ks], bfr[n][ks], acc[m][n], 0, 0, 0);
        __syncthreads();
    }

    // epilogue: C/D mapping col = lane&15, row = (lane>>4)*4 + reg; write fp8 e4m3
    const int rgrp = (lane >> 4) * 4;
    const int cc = lane & 15;
    #pragma unroll
    for (int m = 0; m < 4; ++m) {
        #pragma unroll
        for (int r = 0; r < 4; ++r) {
            int grow = row_base + wm * 64 + m * 16 + rgrp + r;
            float g = dinv[grow];
            #pragma unroll
            for (int n = 0; n < 4; ++n) {
                int gcol = col_base + wn * 64 + n * 16 + cc;
                float v = acc[m][n][r] * g;
                unsigned int p = __builtin_amdgcn_cvt_pk_fp8_f32(v, v, 0u, false);
                hs8[(size_t)grow * HID + gcol] = (unsigned char)p;
            }
        }
    }
}

// ---------------- fused gather-aggregate + scale + b + residual + LayerNorm --------
__device__ __forceinline__ void dec8(u32x2 v, float* acc) {
    f32x2 a = __builtin_amdgcn_cvt_pk_f32_fp8(v[0], false);
    f32x2 b = __builtin_amdgcn_cvt_pk_f32_fp8(v[0], true);
    f32x2 c = __builtin_amdgcn_cvt_pk_f32_fp8(v[1], false);
    f32x2 d = __builtin_amdgcn_cvt_pk_f32_fp8(v[1], true);
    acc[0] += a[0]; acc[1] += a[1]; acc[2] += b[0]; acc[3] += b[1];
    acc[4] += c[0]; acc[5] += c[1]; acc[6] += d[0]; acc[7] += d[1];
}

__global__ __launch_bounds__(256) void agg_ln(const unsigned char* __restrict__ hs8,
                                              const float* __restrict__ resid,
                                              const float* __restrict__ bvec,
                                              const float* __restrict__ gamma,
                                              const float* __restrict__ beta,
                                              const int* __restrict__ rowstart,
                                              const int* __restrict__ cnt,
                                              const float* __restrict__ dinv,
                                              const int* __restrict__ csr,
                                              float* __restrict__ out, int nn) {
    const int wave = threadIdx.x >> 6;
    const int lane = threadIdx.x & 63;
    const int n = blockIdx.x * 4 + wave;
    if (n >= nn) return;
    const int c0 = lane * 8;

    float acc[8];
    #pragma unroll
    for (int j = 0; j < 8; ++j) acc[j] = 0.f;
    // self-loop message (hs8 already includes dinv[src])
    dec8(*(const u32x2*)(hs8 + (size_t)n * HID + c0), acc);

    const int s0 = rowstart[n];
    const int m = cnt[n];
    const int* idx = csr + s0;
    int i = 0;
    for (; i + 8 <= m; i += 8) {
        u32x2 v0 = *(const u32x2*)(hs8 + (size_t)idx[i]     * HID + c0);
        u32x2 v1 = *(const u32x2*)(hs8 + (size_t)idx[i + 1] * HID + c0);
        u32x2 v2 = *(const u32x2*)(hs8 + (size_t)idx[i + 2] * HID + c0);
        u32x2 v3 = *(const u32x2*)(hs8 + (size_t)idx[i + 3] * HID + c0);
        u32x2 v4 = *(const u32x2*)(hs8 + (size_t)idx[i + 4] * HID + c0);
        u32x2 v5 = *(const u32x2*)(hs8 + (size_t)idx[i + 5] * HID + c0);
        u32x2 v6 = *(const u32x2*)(hs8 + (size_t)idx[i + 6] * HID + c0);
        u32x2 v7 = *(const u32x2*)(hs8 + (size_t)idx[i + 7] * HID + c0);
        dec8(v0, acc); dec8(v1, acc); dec8(v2, acc); dec8(v3, acc);
        dec8(v4, acc); dec8(v5, acc); dec8(v6, acc); dec8(v7, acc);
    }
    for (; i < m; ++i)
        dec8(*(const u32x2*)(hs8 + (size_t)idx[i] * HID + c0), acc);

    const float g = dinv[n];
    f32x4 r0 = __builtin_nontemporal_load((const f32x4*)(resid + (size_t)n * HID + c0));
    f32x4 r1 = __builtin_nontemporal_load((const f32x4*)(resid + (size_t)n * HID + c0 + 4));
    float val[8];
    #pragma unroll
    for (int j = 0; j < 4; ++j) {
        val[j]     = r0[j] + g * acc[j]     + bvec[c0 + j];
        val[j + 4] = r1[j] + g * acc[j + 4] + bvec[c0 + j + 4];
    }

    float s = 0.f, q = 0.f;
    #pragma unroll
    for (int j = 0; j < 8; ++j) { s += val[j]; q += val[j] * val[j]; }
    #pragma unroll
    for (int off = 32; off > 0; off >>= 1) {
        s += __shfl_xor(s, off, 64);
        q += __shfl_xor(q, off, 64);
    }
    const float mean = s * (1.f / 512.f);
    const float var = q * (1.f / 512.f) - mean * mean;
    const float rstd = rsqrtf(var + 1e-5f);

    f32x4 o0, o1;
    #pragma unroll
    for (int j = 0; j < 4; ++j) {
        o0[j] = (val[j]     - mean) * rstd * gamma[c0 + j]     + beta[c0 + j];
        o1[j] = (val[j + 4] - mean) * rstd * gamma[c0 + j + 4] + beta[c0 + j + 4];
    }
    __builtin_nontemporal_store(o0, (f32x4*)(out + (size_t)n * HID + c0));
    __builtin_nontemporal_store(o1, (f32x4*)(out + (size_t)n * HID + c0 + 4));
}

extern "C" void kernel_launch(void* const* d_in, const int* in_sizes, int n_in,
                              void* d_out, int out_size, void* d_ws, size_t ws_size,
                              hipStream_t stream) {
    const float* X     = (const float*)d_in[0];   // label_emb [N][512], also residual
    const int*   edges = (const int*)d_in[1];     // [2][E]
    const float* W     = (const float*)d_in[2];   // [512][512]
    const float* b     = (const float*)d_in[3];
    const float* gamma = (const float*)d_in[4];
    const float* beta  = (const float*)d_in[5];
    float* out = (float*)d_out;

    const int E = in_sizes[1] / 2;
    const int N = in_sizes[0] / HID;
    // M_pad multiple of 256 -> nwg = (M_pad/128)*4 divisible by 8 -> bijective XCD swizzle
    const int M_pad = ((N + 255) / 256) * 256;
    const int* src = edges;
    const int* dst = edges + E;

    // workspace layout
    char* w = (char*)d_ws;
    auto alloc = [&](size_t bytes) { char* p = w; w += (bytes + 255) & ~(size_t)255; return p; };
    int*   cnt      = (int*)alloc((size_t)N * 4);
    int*   fill     = (int*)alloc((size_t)N * 4);
    int*   rowstart = (int*)alloc((size_t)N * 4);
    int*   bsum     = (int*)alloc(256 * 4);
    float* dinv     = (float*)alloc((size_t)M_pad * 4);
    int*   csr      = (int*)alloc((size_t)E * 4);
    unsigned short* Wt = (unsigned short*)alloc((size_t)HID * HID * 2);
    unsigned char*  hs8 = (unsigned char*)alloc((size_t)M_pad * HID);
    // Xbf lives in d_out (free until agg_ln; GEMM consumed it by then)
    unsigned short* Xbf = (unsigned short*)d_out;

    init_counts<<<(N + 255) / 256, 256, 0, stream>>>(cnt, fill, N);
    count_deg<<<(E + 255) / 256, 256, 0, stream>>>(dst, cnt, E);
    const int nb = (N + 1023) / 1024;
    scan1<<<nb, 1024, 0, stream>>>(cnt, rowstart, bsum, N);
    scan2<<<1, 64, 0, stream>>>(bsum, nb);
    scan3<<<(N + 255) / 256, 256, 0, stream>>>(rowstart, bsum, cnt, dinv, N);
    csr_fill<<<(E + 255) / 256, 256, 0, stream>>>(src, dst, rowstart, fill, csr, E);
    w_transpose<<<(HID * HID) / 256, 256, 0, stream>>>(W, Wt);
    const int pad_elems = M_pad * HID;
    x_to_bf16<<<(pad_elems / 8 + 255) / 256, 256, 0, stream>>>(X, Xbf, N * HID, pad_elems);
    const int nwg = (M_pad / 128) * NWGX;   // divisible by 8
    gemm_xw<<<nwg, 256, 0, stream>>>(Xbf, Wt, dinv, hs8, nwg);
    agg_ln<<<(N + 3) / 4, 256, 0, stream>>>(hs8, X, b, gamma, beta, rowstart, cnt, dinv, csr, out, N);
}